// Round 1
// baseline (231.542 us; speedup 1.0000x reference)
//
#include <hip/hip_runtime.h>
#include <hip/hip_bf16.h>

// Problem: y = q_tok(x) @ q_grp(W)^T + bias
//   x: [2,1024,4096] f32 -> M=2048 tokens, K=4096
//   W: [4096,4096] f32   -> N=4096 outs, per-group(128 along K) quant
//   bias: [4096] f32, out: [2048,4096] f32
//
// Pipeline: quant_x -> ws (bf16, 16MB), quant_w -> ws (bf16, 32MB),
// then m97-style bf16 MFMA GEMM (128x128 tile, BK=32, global_load_lds w=16).

#define M_TOK 2048
#define N_OUT 4096
#define K_IN  4096

typedef __attribute__((ext_vector_type(8))) short short8;
typedef __attribute__((ext_vector_type(4))) float floatx4;

// ---------- fp4 e2m1 nearest-grid (grid: 0,.5,1,1.5,2,3,4,6 with sign) ----------
__device__ __forceinline__ float nearest_grid(float v) {
    float a = fabsf(v);
    float g = a < 0.25f ? 0.0f
            : a < 0.75f ? 0.5f
            : a < 1.25f ? 1.0f
            : a < 1.75f ? 1.5f
            : a < 2.5f  ? 2.0f
            : a < 3.5f  ? 3.0f
            : a < 5.0f  ? 4.0f
            : 6.0f;
    return copysignf(g, v);
}

__device__ __forceinline__ unsigned short f2bf(float f) {
    __hip_bfloat16 h = __float2bfloat16(f);  // RNE
    return *reinterpret_cast<unsigned short*>(&h);
}

// ---------- per-token activation quant: clamp [-3,3], scale=absmax/6 ----------
__global__ __launch_bounds__(256) void quant_x_kernel(
    const float* __restrict__ x, unsigned short* __restrict__ xq)
{
    const int row = blockIdx.x;          // 0..2047
    const int t   = threadIdx.x;         // 0..255
    const int lane = t & 63, wid = t >> 6;
    const float* xr = x + (size_t)row * K_IN;

    float vals[16];
    float amax = 0.0f;
    #pragma unroll
    for (int i = 0; i < 4; i++) {
        float4 v = *(const float4*)(xr + i * 1024 + t * 4);
        v.x = fminf(fmaxf(v.x, -3.0f), 3.0f);
        v.y = fminf(fmaxf(v.y, -3.0f), 3.0f);
        v.z = fminf(fmaxf(v.z, -3.0f), 3.0f);
        v.w = fminf(fmaxf(v.w, -3.0f), 3.0f);
        vals[i*4+0] = v.x; vals[i*4+1] = v.y; vals[i*4+2] = v.z; vals[i*4+3] = v.w;
        amax = fmaxf(amax, fmaxf(fmaxf(fabsf(v.x), fabsf(v.y)),
                                 fmaxf(fabsf(v.z), fabsf(v.w))));
    }
    #pragma unroll
    for (int off = 32; off; off >>= 1)
        amax = fmaxf(amax, __shfl_xor(amax, off));
    __shared__ float smax[4];
    if (lane == 0) smax[wid] = amax;
    __syncthreads();
    amax = fmaxf(fmaxf(smax[0], smax[1]), fmaxf(smax[2], smax[3]));

    const float scale = amax / 6.0f;     // match reference: amax/6.0, then x/scale
    unsigned short* xo = xq + (size_t)row * K_IN;
    #pragma unroll
    for (int i = 0; i < 4; i++) {
        ushort4 u;
        u.x = f2bf(nearest_grid(vals[i*4+0] / scale) * scale);
        u.y = f2bf(nearest_grid(vals[i*4+1] / scale) * scale);
        u.z = f2bf(nearest_grid(vals[i*4+2] / scale) * scale);
        u.w = f2bf(nearest_grid(vals[i*4+3] / scale) * scale);
        *(ushort4*)(xo + i * 1024 + t * 4) = u;
    }
}

// ---------- per-group weight quant: groups of 128 along K, scale=absmax/6 ----------
__global__ __launch_bounds__(256) void quant_w_kernel(
    const float* __restrict__ w, unsigned short* __restrict__ wq)
{
    const int t = threadIdx.x;
    const int lane = t & 63, wid = t >> 6;
    const size_t g = (size_t)blockIdx.x * 4 + wid;   // group id, 0..131071
    const float* base = w + g * 128;
    float2 v = *(const float2*)(base + lane * 2);
    float amax = fmaxf(fabsf(v.x), fabsf(v.y));
    #pragma unroll
    for (int off = 32; off; off >>= 1)
        amax = fmaxf(amax, __shfl_xor(amax, off));
    const float scale = amax / 6.0f;
    ushort2 u;
    u.x = f2bf(nearest_grid(v.x / scale) * scale);
    u.y = f2bf(nearest_grid(v.y / scale) * scale);
    *(ushort2*)(wq + g * 128 + lane * 2) = u;
}

// ---------- async 16B global->LDS ----------
__device__ __forceinline__ void gld16(const unsigned short* g, unsigned short* l) {
    __builtin_amdgcn_global_load_lds(
        (const __attribute__((address_space(1))) void*)g,
        (__attribute__((address_space(3))) void*)l, 16, 0, 0);
}

// ---------- m97-style bf16 GEMM: C[M,N] = A[M,K] * B[N,K]^T + bias ----------
__global__ __launch_bounds__(256) void gemm_bt_kernel(
    const unsigned short* __restrict__ A,   // xq [2048][4096] bf16 bits
    const unsigned short* __restrict__ B,   // wq [4096][4096] bf16 bits
    const float* __restrict__ bias,
    float* __restrict__ C)
{
    __shared__ unsigned short As[128 * 32]; // 8 KB, row-major [row][k]
    __shared__ unsigned short Bs[128 * 32]; // 8 KB

    const int tid = threadIdx.x;
    const int m0 = blockIdx.y * 128;
    const int n0 = blockIdx.x * 128;

    const int lane = tid & 63;
    const int wid  = tid >> 6;
    const int wm = (wid & 1) * 64;   // wave 2x2 grid over 128x128 tile
    const int wn = (wid >> 1) * 64;
    const int lr = lane & 15;
    const int lq = lane >> 4;

    floatx4 acc[4][4] = {};

    // staging: 128x32 halves = 512 x 16B chunks; 256 threads x 2 chunks each.
    // chunk c covers halves [c*8, c*8+8) of the row-major tile -> LDS byte c*16
    // = wave-uniform base + lane*16 (global_load_lds constraint satisfied).
    const int f0 = tid * 8;          // chunk tid
    const int f1 = f0 + 2048;        // chunk tid+256
    const int r0 = f0 >> 5, c0 = f0 & 31;
    const int r1 = f1 >> 5, c1 = f1 & 31;
    const unsigned short* gA0 = A + (size_t)(m0 + r0) * K_IN + c0;
    const unsigned short* gA1 = A + (size_t)(m0 + r1) * K_IN + c1;
    const unsigned short* gB0 = B + (size_t)(n0 + r0) * K_IN + c0;
    const unsigned short* gB1 = B + (size_t)(n0 + r1) * K_IN + c1;

    for (int k0 = 0; k0 < K_IN; k0 += 32) {
        gld16(gA0 + k0, As + f0);
        gld16(gA1 + k0, As + f1);
        gld16(gB0 + k0, Bs + f0);
        gld16(gB1 + k0, Bs + f1);
        __syncthreads();   // compiler emits s_waitcnt vmcnt(0) before s_barrier

        short8 af[4], bf[4];
        #pragma unroll
        for (int mi = 0; mi < 4; mi++)   // A frag: A[m=lane&15][k=lq*8 + j]
            af[mi] = *(const short8*)(As + (wm + mi * 16 + lr) * 32 + lq * 8);
        #pragma unroll
        for (int ni = 0; ni < 4; ni++)   // B frag: B[n=lane&15][k=lq*8 + j]
            bf[ni] = *(const short8*)(Bs + (wn + ni * 16 + lr) * 32 + lq * 8);

        #pragma unroll
        for (int mi = 0; mi < 4; mi++)
            #pragma unroll
            for (int ni = 0; ni < 4; ni++)
                acc[mi][ni] = __builtin_amdgcn_mfma_f32_16x16x32_bf16(
                    af[mi], bf[ni], acc[mi][ni], 0, 0, 0);
        __syncthreads();
    }

    // epilogue: C/D layout col=lane&15, row=(lane>>4)*4+reg  [m89/m91 verified]
    #pragma unroll
    for (int mi = 0; mi < 4; mi++) {
        const int rbase = m0 + wm + mi * 16 + lq * 4;
        #pragma unroll
        for (int ni = 0; ni < 4; ni++) {
            const int col = n0 + wn + ni * 16 + lr;
            const float bb = bias[col];
            #pragma unroll
            for (int r = 0; r < 4; r++)
                C[(size_t)(rbase + r) * N_OUT + col] = acc[mi][ni][r] + bb;
        }
    }
}

extern "C" void kernel_launch(void* const* d_in, const int* in_sizes, int n_in,
                              void* d_out, int out_size, void* d_ws, size_t ws_size,
                              hipStream_t stream) {
    const float* x    = (const float*)d_in[0];   // 2*1024*4096
    const float* w    = (const float*)d_in[1];   // 4096*4096
    const float* bias = (const float*)d_in[2];   // 4096
    float* out = (float*)d_out;                  // 2048*4096 f32

    // workspace: xq (16 MB) then wq (32 MB), both bf16 bit-patterns
    unsigned short* xq = (unsigned short*)d_ws;
    unsigned short* wq = xq + (size_t)M_TOK * K_IN;

    quant_x_kernel<<<M_TOK, 256, 0, stream>>>(x, xq);
    quant_w_kernel<<<(N_OUT * (K_IN / 128)) / 4, 256, 0, stream>>>(w, wq);
    gemm_bt_kernel<<<dim3(N_OUT / 128, M_TOK / 128), 256, 0, stream>>>(xq, wq, bias, out);
}

// Round 2
// 211.493 us; speedup vs baseline: 1.0948x; 1.0948x over previous
//
#include <hip/hip_runtime.h>
#include <hip/hip_bf16.h>

// y = q_tok(x) @ q_grp(W)^T + bias
//   x: [2048,4096] f32, W: [4096,4096] f32 (per-group-128 quant), bias [4096]
// R2: fused quant launch; GEMM 128x128 tile with 512 threads (8 waves x 64x32)
// for 16 waves/CU, + LDS chunk swizzle to kill ds_read_b128 bank conflicts.

#define M_TOK 2048
#define N_OUT 4096
#define K_IN  4096
#define XBLK  2048    // quant_x role blocks (one per token row)
#define WBLK  16384   // quant_w role blocks (8 groups of 128 each)

typedef __attribute__((ext_vector_type(8))) short short8;
typedef __attribute__((ext_vector_type(4))) float floatx4;

// ---------- fp4 e2m1 nearest-grid (0,.5,1,1.5,2,3,4,6 with sign) ----------
__device__ __forceinline__ float nearest_grid(float v) {
    float a = fabsf(v);
    float g = a < 0.25f ? 0.0f
            : a < 0.75f ? 0.5f
            : a < 1.25f ? 1.0f
            : a < 1.75f ? 1.5f
            : a < 2.5f  ? 2.0f
            : a < 3.5f  ? 3.0f
            : a < 5.0f  ? 4.0f
            : 6.0f;
    return copysignf(g, v);
}

__device__ __forceinline__ unsigned short f2bf(float f) {
    __hip_bfloat16 h = __float2bfloat16(f);  // RNE
    return *reinterpret_cast<unsigned short*>(&h);
}

// ---------- fused quant: blocks [0,XBLK) do per-token x, rest do per-group w ----------
__global__ __launch_bounds__(256) void quant_fused_kernel(
    const float* __restrict__ x, const float* __restrict__ w,
    unsigned short* __restrict__ xq, unsigned short* __restrict__ wq)
{
    const int t = threadIdx.x;
    const int lane = t & 63, wid = t >> 6;

    if (blockIdx.x < XBLK) {
        // per-token: clamp [-3,3], scale = absmax/6 over row of 4096
        const int row = blockIdx.x;
        const float* xr = x + (size_t)row * K_IN;
        float vals[16];
        float amax = 0.0f;
        #pragma unroll
        for (int i = 0; i < 4; i++) {
            float4 v = *(const float4*)(xr + i * 1024 + t * 4);
            v.x = fminf(fmaxf(v.x, -3.0f), 3.0f);
            v.y = fminf(fmaxf(v.y, -3.0f), 3.0f);
            v.z = fminf(fmaxf(v.z, -3.0f), 3.0f);
            v.w = fminf(fmaxf(v.w, -3.0f), 3.0f);
            vals[i*4+0] = v.x; vals[i*4+1] = v.y; vals[i*4+2] = v.z; vals[i*4+3] = v.w;
            amax = fmaxf(amax, fmaxf(fmaxf(fabsf(v.x), fabsf(v.y)),
                                     fmaxf(fabsf(v.z), fabsf(v.w))));
        }
        #pragma unroll
        for (int off = 32; off; off >>= 1)
            amax = fmaxf(amax, __shfl_xor(amax, off));
        __shared__ float smax[4];
        if (lane == 0) smax[wid] = amax;
        __syncthreads();
        amax = fmaxf(fmaxf(smax[0], smax[1]), fmaxf(smax[2], smax[3]));

        const float scale = amax / 6.0f;   // IEEE div x/scale to match np exactly
        unsigned short* xo = xq + (size_t)row * K_IN;
        #pragma unroll
        for (int i = 0; i < 4; i++) {
            ushort4 u;
            u.x = f2bf(nearest_grid(vals[i*4+0] / scale) * scale);
            u.y = f2bf(nearest_grid(vals[i*4+1] / scale) * scale);
            u.z = f2bf(nearest_grid(vals[i*4+2] / scale) * scale);
            u.w = f2bf(nearest_grid(vals[i*4+3] / scale) * scale);
            *(ushort4*)(xo + i * 1024 + t * 4) = u;
        }
    } else {
        // per-group w: block covers 1024 floats = 8 groups; half-wave per group
        const int b = blockIdx.x - XBLK;
        const float* base = w + (size_t)b * 1024 + t * 4;
        float4 v = *(const float4*)base;
        float amax = fmaxf(fmaxf(fabsf(v.x), fabsf(v.y)),
                           fmaxf(fabsf(v.z), fabsf(v.w)));
        #pragma unroll
        for (int off = 16; off; off >>= 1)   // reduce within 32-lane half = group
            amax = fmaxf(amax, __shfl_xor(amax, off));
        const float scale = amax / 6.0f;
        ushort4 u;
        u.x = f2bf(nearest_grid(v.x / scale) * scale);
        u.y = f2bf(nearest_grid(v.y / scale) * scale);
        u.z = f2bf(nearest_grid(v.z / scale) * scale);
        u.w = f2bf(nearest_grid(v.w / scale) * scale);
        *(ushort4*)(wq + (size_t)b * 1024 + t * 4) = u;
    }
}

// ---------- async 16B global->LDS ----------
__device__ __forceinline__ void gld16(const unsigned short* g, unsigned short* l) {
    __builtin_amdgcn_global_load_lds(
        (const __attribute__((address_space(1))) void*)g,
        (__attribute__((address_space(3))) void*)l, 16, 0, 0);
}

// ---------- bf16 GEMM: C[M,N] = A[M,K] * B[N,K]^T + bias ----------
// 128x128 tile, 512 threads (8 waves, each a 64x32 quadrant of 16x16x32 MFMAs).
// LDS tile: row-major 128 rows x 4 chunks(16B). Chunk swizzle:
//   phys_col p = (logical_col + ((row>>1)&3)) & 3
// applied on the GLOBAL source address during staging (LDS dest stays
// wave-uniform + lane*16 per the global_load_lds constraint), and on the
// LDS address during fragment reads -> max 2-way bank aliasing (free).
__global__ __launch_bounds__(512) void gemm_bt_kernel(
    const unsigned short* __restrict__ A,   // xq [2048][4096]
    const unsigned short* __restrict__ B,   // wq [4096][4096]
    const float* __restrict__ bias,
    float* __restrict__ C)
{
    __shared__ unsigned short As[128 * 32]; // 8 KB
    __shared__ unsigned short Bs[128 * 32]; // 8 KB

    const int tid = threadIdx.x;
    const int m0 = blockIdx.y * 128;
    const int n0 = blockIdx.x * 128;
    const int lane = tid & 63;
    const int wid  = tid >> 6;          // 0..7
    const int wm = (wid & 1) * 64;      // 2 x 4 wave grid: 64x32 per wave
    const int wn = (wid >> 1) * 32;
    const int lr = lane & 15;
    const int lq = lane >> 4;

    floatx4 acc[4][2] = {};

    // staging: one 16B chunk per thread per buffer; phys chunk idx = tid
    const int pr = tid >> 2;                       // row 0..127
    const int pc = tid & 3;                        // phys chunk col
    const int lc = (pc - ((pr >> 1) & 3)) & 3;     // logical chunk col
    const int f0 = tid * 8;                        // LDS dest (halves)
    const unsigned short* gA = A + (size_t)(m0 + pr) * K_IN + lc * 8;
    const unsigned short* gB = B + (size_t)(n0 + pr) * K_IN + lc * 8;

    for (int k0 = 0; k0 < K_IN; k0 += 32) {
        gld16(gA + k0, As + f0);
        gld16(gB + k0, Bs + f0);
        __syncthreads();

        short8 af[4], bf[2];
        #pragma unroll
        for (int mi = 0; mi < 4; mi++) {
            const int row = wm + mi * 16 + lr;
            const int p = (lq + ((row >> 1) & 3)) & 3;
            af[mi] = *(const short8*)(As + row * 32 + p * 8);
        }
        #pragma unroll
        for (int ni = 0; ni < 2; ni++) {
            const int row = wn + ni * 16 + lr;
            const int p = (lq + ((row >> 1) & 3)) & 3;
            bf[ni] = *(const short8*)(Bs + row * 32 + p * 8);
        }

        #pragma unroll
        for (int mi = 0; mi < 4; mi++)
            #pragma unroll
            for (int ni = 0; ni < 2; ni++)
                acc[mi][ni] = __builtin_amdgcn_mfma_f32_16x16x32_bf16(
                    af[mi], bf[ni], acc[mi][ni], 0, 0, 0);
        __syncthreads();
    }

    // epilogue: C/D layout col=lane&15, row=(lane>>4)*4+reg [m89/m91]
    #pragma unroll
    for (int mi = 0; mi < 4; mi++) {
        const int rbase = m0 + wm + mi * 16 + lq * 4;
        #pragma unroll
        for (int ni = 0; ni < 2; ni++) {
            const int col = n0 + wn + ni * 16 + lr;
            const float bb = bias[col];
            #pragma unroll
            for (int r = 0; r < 4; r++)
                C[(size_t)(rbase + r) * N_OUT + col] = acc[mi][ni][r] + bb;
        }
    }
}

extern "C" void kernel_launch(void* const* d_in, const int* in_sizes, int n_in,
                              void* d_out, int out_size, void* d_ws, size_t ws_size,
                              hipStream_t stream) {
    const float* x    = (const float*)d_in[0];
    const float* w    = (const float*)d_in[1];
    const float* bias = (const float*)d_in[2];
    float* out = (float*)d_out;

    unsigned short* xq = (unsigned short*)d_ws;                 // 16 MB
    unsigned short* wq = xq + (size_t)M_TOK * K_IN;             // 32 MB

    quant_fused_kernel<<<XBLK + WBLK, 256, 0, stream>>>(x, w, xq, wq);
    gemm_bt_kernel<<<dim3(N_OUT / 128, M_TOK / 128), 512, 0, stream>>>(xq, wq, bias, out);
}

// Round 3
// 209.938 us; speedup vs baseline: 1.1029x; 1.0074x over previous
//
#include <hip/hip_runtime.h>
#include <hip/hip_bf16.h>

// y = q_tok(x) @ q_grp(W)^T + bias, factored exactly:
//   q(x) = g_x * s_x[m]      (g in fp4 grid, exact in e4m3)
//   q(W) = g_w * s_w[n,grp]  (grp = 128 along K)
//   y[m,n] = s_x[m] * sum_grp s_w[n,grp] * (sum_{k in grp} g_x g_w)
// Inner sums via mfma_f32_16x16x32_fp8_fp8 (EXACT: grid products are
// multiples of 0.25, fp32 accum). R2 was LDS-BW-bound (16.6 MB/CU of
// ds_read); fp8 halves fragment bytes -> ~8 MB/CU.

#define M_TOK 2048
#define N_OUT 4096
#define K_IN  4096
#define XBLK  2048
#define WBLK  16384

typedef __attribute__((ext_vector_type(4))) float floatx4;

// fp4-e2m1 nearest-grid value of v, encoded directly as OCP e4m3 byte.
// 0->0x00, .5->0x30, 1->0x38, 1.5->0x3C, 2->0x40, 3->0x44, 4->0x48, 6->0x4C
__device__ __forceinline__ unsigned int q_fp8(float v) {
    float a = fabsf(v);
    unsigned int m =
        a < 0.25f ? 0x00u :
        a < 0.75f ? 0x30u :
        a < 1.25f ? 0x38u :
        a < 1.75f ? 0x3Cu :
        a < 2.5f  ? 0x40u :
        a < 3.5f  ? 0x44u :
        a < 5.0f  ? 0x48u :
                    0x4Cu;
    return m | ((__float_as_uint(v) >> 24) & 0x80u);
}

// ---------- fused quant: blocks [0,XBLK) per-token x, rest per-group w ----------
__global__ __launch_bounds__(256) void quant_fused_kernel(
    const float* __restrict__ x, const float* __restrict__ w,
    unsigned char* __restrict__ xq, float* __restrict__ sx,
    unsigned char* __restrict__ wq, float* __restrict__ sw)
{
    const int t = threadIdx.x;
    const int lane = t & 63, wid = t >> 6;

    if (blockIdx.x < XBLK) {
        const int row = blockIdx.x;
        const float* xr = x + (size_t)row * K_IN;
        float vals[16];
        float amax = 0.0f;
        #pragma unroll
        for (int i = 0; i < 4; i++) {
            float4 v = *(const float4*)(xr + i * 1024 + t * 4);
            v.x = fminf(fmaxf(v.x, -3.0f), 3.0f);
            v.y = fminf(fmaxf(v.y, -3.0f), 3.0f);
            v.z = fminf(fmaxf(v.z, -3.0f), 3.0f);
            v.w = fminf(fmaxf(v.w, -3.0f), 3.0f);
            vals[i*4+0] = v.x; vals[i*4+1] = v.y; vals[i*4+2] = v.z; vals[i*4+3] = v.w;
            amax = fmaxf(amax, fmaxf(fmaxf(fabsf(v.x), fabsf(v.y)),
                                     fmaxf(fabsf(v.z), fabsf(v.w))));
        }
        #pragma unroll
        for (int off = 32; off; off >>= 1)
            amax = fmaxf(amax, __shfl_xor(amax, off));
        __shared__ float smax[4];
        if (lane == 0) smax[wid] = amax;
        __syncthreads();
        amax = fmaxf(fmaxf(smax[0], smax[1]), fmaxf(smax[2], smax[3]));

        const float scale = amax / 6.0f;
        if (t == 0) sx[row] = scale;
        unsigned char* xo = xq + (size_t)row * K_IN;
        #pragma unroll
        for (int i = 0; i < 4; i++) {
            unsigned int u = q_fp8(vals[i*4+0] / scale)
                           | (q_fp8(vals[i*4+1] / scale) << 8)
                           | (q_fp8(vals[i*4+2] / scale) << 16)
                           | (q_fp8(vals[i*4+3] / scale) << 24);
            *(unsigned int*)(xo + i * 1024 + t * 4) = u;
        }
    } else {
        // block covers 1024 floats = 8 groups of 128; 32-lane cluster per group
        const int b = blockIdx.x - XBLK;
        const float* base = w + (size_t)b * 1024 + t * 4;
        float4 v = *(const float4*)base;
        float amax = fmaxf(fmaxf(fabsf(v.x), fabsf(v.y)),
                           fmaxf(fabsf(v.z), fabsf(v.w)));
        #pragma unroll
        for (int off = 16; off; off >>= 1)
            amax = fmaxf(amax, __shfl_xor(amax, off));
        const float scale = amax / 6.0f;
        if ((lane & 31) == 0) sw[b * 8 + (t >> 5)] = scale;   // flat grp id = n*32+g
        unsigned int u = q_fp8(v.x / scale)
                       | (q_fp8(v.y / scale) << 8)
                       | (q_fp8(v.z / scale) << 16)
                       | (q_fp8(v.w / scale) << 24);
        *(unsigned int*)(wq + (size_t)b * 1024 + t * 4) = u;
    }
}

// ---------- async 16B global->LDS ----------
__device__ __forceinline__ void gld16(const unsigned char* g, unsigned char* l) {
    __builtin_amdgcn_global_load_lds(
        (const __attribute__((address_space(1))) void*)g,
        (__attribute__((address_space(3))) void*)l, 16, 0, 0);
}

// ---------- fp8 GEMM with per-group rescale ----------
// 128x128 tile, 512 threads, 8 waves of 64x32. BK=64 (2 MFMA k-steps/stage).
// LDS row = 64 fp8 = 4 chunks(16B); swizzle phys=(chunk+(row>>1))&3 -> b64
// fragment reads land 2 words/bank (free, m136).
__global__ __launch_bounds__(512) void gemm_fp8_kernel(
    const unsigned char* __restrict__ A, const float* __restrict__ sx,
    const unsigned char* __restrict__ B, const float* __restrict__ sw,
    const float* __restrict__ bias, float* __restrict__ C)
{
    __shared__ unsigned char As[128 * 64]; // 8 KB
    __shared__ unsigned char Bs[128 * 64]; // 8 KB

    const int tid = threadIdx.x;
    const int m0 = blockIdx.y * 128;
    const int n0 = blockIdx.x * 128;
    const int lane = tid & 63;
    const int wid  = tid >> 6;
    const int wm = (wid & 1) * 64;
    const int wn = (wid >> 1) * 32;
    const int lr = lane & 15;
    const int lq = lane >> 4;

    floatx4 mast[4][2] = {};

    // staging: thread t -> phys chunk t of both As and Bs (dest = tid*16,
    // wave-uniform + lane*16 ok); inverse swizzle on global source.
    const int pr = tid >> 2;
    const int pc = tid & 3;
    const int lc = (pc - (pr >> 1)) & 3;
    const unsigned char* gA = A + (size_t)(m0 + pr) * K_IN + lc * 16;
    const unsigned char* gB = B + (size_t)(n0 + pr) * K_IN + lc * 16;
    const int f0 = tid * 16;

    const int col0 = n0 + wn + lr;
    const float* swp0 = sw + (size_t)col0 * 32;
    const float* swp1 = sw + (size_t)(col0 + 16) * 32;

    for (int g = 0; g < 32; g++) {
        floatx4 acc[4][2] = {};
        #pragma unroll
        for (int half = 0; half < 2; half++) {
            const int k0 = g * 128 + half * 64;
            gld16(gA + k0, As + f0);
            gld16(gB + k0, Bs + f0);
            __syncthreads();

            #pragma unroll
            for (int s = 0; s < 2; s++) {
                long af[4], bf[2];
                #pragma unroll
                for (int mi = 0; mi < 4; mi++) {
                    const int row = wm + mi * 16 + lr;
                    const int p = ((s * 2 + (lq >> 1)) + (row >> 1)) & 3;
                    af[mi] = *(const long*)(As + row * 64 + p * 16 + (lq & 1) * 8);
                }
                #pragma unroll
                for (int ni = 0; ni < 2; ni++) {
                    const int row = wn + ni * 16 + lr;
                    const int p = ((s * 2 + (lq >> 1)) + (row >> 1)) & 3;
                    bf[ni] = *(const long*)(Bs + row * 64 + p * 16 + (lq & 1) * 8);
                }
                #pragma unroll
                for (int mi = 0; mi < 4; mi++)
                    #pragma unroll
                    for (int ni = 0; ni < 2; ni++)
                        acc[mi][ni] = __builtin_amdgcn_mfma_f32_16x16x32_fp8_fp8(
                            af[mi], bf[ni], acc[mi][ni], 0, 0, 0);
            }
            __syncthreads();
        }
        const float sw0 = swp0[g];
        const float sw1 = swp1[g];
        #pragma unroll
        for (int mi = 0; mi < 4; mi++)
            #pragma unroll
            for (int r = 0; r < 4; r++) {
                mast[mi][0][r] += sw0 * acc[mi][0][r];
                mast[mi][1][r] += sw1 * acc[mi][1][r];
            }
    }

    // epilogue: C/D layout col=lane&15, row=(lane>>4)*4+reg
    #pragma unroll
    for (int mi = 0; mi < 4; mi++) {
        const int rbase = m0 + wm + mi * 16 + lq * 4;
        #pragma unroll
        for (int ni = 0; ni < 2; ni++) {
            const int col = n0 + wn + ni * 16 + lr;
            const float bb = bias[col];
            #pragma unroll
            for (int r = 0; r < 4; r++)
                C[(size_t)(rbase + r) * N_OUT + col] =
                    sx[rbase + r] * mast[mi][ni][r] + bb;
        }
    }
}

extern "C" void kernel_launch(void* const* d_in, const int* in_sizes, int n_in,
                              void* d_out, int out_size, void* d_ws, size_t ws_size,
                              hipStream_t stream) {
    const float* x    = (const float*)d_in[0];
    const float* w    = (const float*)d_in[1];
    const float* bias = (const float*)d_in[2];
    float* out = (float*)d_out;

    unsigned char* xq = (unsigned char*)d_ws;                       // 8 MB
    unsigned char* wq = xq + (size_t)M_TOK * K_IN;                  // 16 MB
    float* sw = (float*)(wq + (size_t)N_OUT * K_IN);                // 512 KB
    float* sx = sw + (size_t)N_OUT * (K_IN / 128);                  // 8 KB

    quant_fused_kernel<<<XBLK + WBLK, 256, 0, stream>>>(x, w, xq, sx, wq, sw);
    gemm_fp8_kernel<<<dim3(N_OUT / 128, M_TOK / 128), 512, 0, stream>>>(
        xq, sx, wq, sw, bias, out);
}